// Round 7
// baseline (748.630 us; speedup 1.0000x reference)
//
#include <hip/hip_runtime.h>
#include <math.h>

#define N_PTS 120000
#define D 256
#define BATCH 2
#define NH 8
#define DH 32
#define OUTC 20

#define Zd 60
#define Yd 45
#define Xd 4
#define Gq 10800
#define Sq 21600

#define Ze 12
#define Ye 24
#define Xe 2
#define Gk 576
#define Sk 1152

typedef __bf16 bf16_t;
typedef __attribute__((ext_vector_type(8))) __bf16 bf16x8;
typedef __attribute__((ext_vector_type(4))) __bf16 bf16x4;
typedef __attribute__((ext_vector_type(4))) float f32x4;

// ---- monotonic float<->uint mapping for atomic max ----
__device__ inline unsigned enc_f(float x) {
    unsigned u = __float_as_uint(x);
    return (u & 0x80000000u) ? ~u : (u | 0x80000000u);
}
__device__ inline float dec_f(unsigned m) {
    return (m & 0x80000000u) ? __uint_as_float(m & 0x7fffffffu)
                             : __uint_as_float(~m);
}

__device__ inline int seg_k_of(const int* id) {
    return ((id[0] * Ze + id[1] / 40) * Ye + id[2] / 15) * Xe + (id[3] >> 4);
}

// ---- weight prep: transpose + fp32->bf16; bkv concat ----
__global__ __launch_bounds__(256) void k_prep(
    const float* __restrict__ Wp, const float* __restrict__ We,
    const float* __restrict__ Wq, const float* __restrict__ Wk,
    const float* __restrict__ Wv, const float* __restrict__ Wo,
    const float* __restrict__ bk, const float* __restrict__ bv,
    bf16_t* __restrict__ Wpt, bf16_t* __restrict__ Wet,
    bf16_t* __restrict__ Wqt, bf16_t* __restrict__ Wkv,
    bf16_t* __restrict__ Wot, float* __restrict__ bkv)
{
    int n = blockIdx.x, k = threadIdx.x;
    if (n < 256) {
        Wpt[n * 256 + k] = (bf16_t)Wp[k * 256 + n];
    } else if (n < 512) {
        int nn = n - 256;
        Wet[nn * 256 + k] = (bf16_t)We[k * 256 + nn];
    } else if (n < 768) {
        int nn = n - 512;
        Wqt[nn * 256 + k] = (bf16_t)Wq[k * 256 + nn];
    } else if (n < 1280) {
        int m2 = n - 768;
        const float* S = (m2 < 256) ? Wk : Wv;
        int nn = m2 & 255;
        Wkv[m2 * 256 + k] = (bf16_t)S[k * 256 + nn];
    } else if (n < 1536) {
        int nn = n - 1280;
        Wot[nn * 256 + k] = (bf16_t)Wo[k * 256 + nn];
    } else {
        bkv[k] = bk[k]; bkv[256 + k] = bv[k];
    }
}

// ---- counting sort by seg_k ----
__global__ __launch_bounds__(256) void k_hist(
    const int* __restrict__ indices, int* __restrict__ cnt)
{
    int i = blockIdx.x * 256 + threadIdx.x;
    if (i < N_PTS) atomicAdd(&cnt[seg_k_of(indices + (size_t)i * 4)], 1);
}

__global__ __launch_bounds__(256) void k_scan(
    const int* __restrict__ cnt, int* __restrict__ off, int* __restrict__ wrk)
{
    __shared__ int buf[256];
    __shared__ int carry;
    int t = threadIdx.x;
    if (t == 0) carry = 0;
    __syncthreads();
    for (int base = 0; base < Sk; base += 256) {
        int idx = base + t;
        int v = (idx < Sk) ? cnt[idx] : 0;
        buf[t] = v;
        __syncthreads();
        for (int o = 1; o < 256; o <<= 1) {
            int x = (t >= o) ? buf[t - o] : 0;
            __syncthreads();
            buf[t] += x;
            __syncthreads();
        }
        int exc = buf[t] - v;
        if (idx < Sk) { int val = carry + exc; off[idx] = val; wrk[idx] = val; }
        __syncthreads();
        if (t == 255) carry += buf[255];
        __syncthreads();
    }
    if (t == 0) off[Sk] = carry;
}

__global__ __launch_bounds__(256) void k_fill(
    const int* __restrict__ indices, int* __restrict__ wrk, int* __restrict__ perm)
{
    int i = blockIdx.x * 256 + threadIdx.x;
    if (i < N_PTS) {
        int pos = atomicAdd(&wrk[seg_k_of(indices + (size_t)i * 4)], 1);
        perm[pos] = i;
    }
}

// ---- MFMA GEMM: [M x 256] fp32 A (optional row-perm) @ Wt[N x 256] bf16 ----
// mode 0: fp32 out + bias; mode 1: pool scatter-max; mode 2: bf16 out + bias.
__global__ __launch_bounds__(512, 2) void k_gemm(
    const float* __restrict__ A, int M,
    const bf16_t* __restrict__ Wt, const float* __restrict__ bias,
    int mode, float* __restrict__ outp, int ldo,
    const int* __restrict__ indices, const int* __restrict__ perm,
    unsigned* __restrict__ poolbits)
{
    __shared__ __align__(16) bf16_t Abuf[128][72];
    __shared__ __align__(16) bf16_t Bbuf[256][72];
    __shared__ int perm_s[128];
    __shared__ int sq_s[128];

    const int t = threadIdx.x;
    const int wave = t >> 6, lane = t & 63;
    const int wr = wave >> 2, wc = wave & 3;
    const int lrow = lane & 15, quad = lane >> 4;
    const int row0 = blockIdx.y * 128;
    const int ntile = blockIdx.x;

    if (t < 128) {
        int row = row0 + t;
        int src = (row < M) ? (perm ? perm[row] : row) : -1;
        perm_s[t] = src;
        if (mode == 1) {
            if (src >= 0) {
                const int* id = indices + (size_t)src * 4;
                sq_s[t] = ((id[0] * Zd + (id[1] >> 3)) * Yd + (id[2] >> 3)) * Xd + (id[3] >> 3);
            } else sq_s[t] = 0;
        }
    }
    __syncthreads();

    f32x4 acc[4][4];
    #pragma unroll
    for (int mi = 0; mi < 4; ++mi)
        #pragma unroll
        for (int ni = 0; ni < 4; ++ni)
            acc[mi][ni] = (f32x4){0.f, 0.f, 0.f, 0.f};

    for (int k0 = 0; k0 < 256; k0 += 64) {
        #pragma unroll
        for (int i = 0; i < 4; ++i) {
            int c = i * 512 + t;
            int r = c >> 4, c4 = c & 15;
            int pr = perm_s[r];
            float4 v = make_float4(0.f, 0.f, 0.f, 0.f);
            if (pr >= 0)
                v = *(const float4*)(A + (size_t)pr * 256 + k0 + c4 * 4);
            bf16x4 bv4;
            bv4[0] = (bf16_t)v.x; bv4[1] = (bf16_t)v.y;
            bv4[2] = (bf16_t)v.z; bv4[3] = (bf16_t)v.w;
            *(bf16x4*)&Abuf[r][c4 * 4] = bv4;
        }
        #pragma unroll
        for (int i = 0; i < 4; ++i) {
            int c = i * 512 + t;
            int r = c >> 3, c8 = c & 7;
            uint4 w = *(const uint4*)(Wt + ((size_t)(ntile * 256 + r)) * 256 + k0 + c8 * 8);
            *(uint4*)&Bbuf[r][c8 * 8] = w;
        }
        __syncthreads();

        #pragma unroll
        for (int kk = 0; kk < 64; kk += 32) {
            bf16x8 Af[4], Bf[4];
            #pragma unroll
            for (int mi = 0; mi < 4; ++mi)
                Af[mi] = *(const bf16x8*)&Abuf[wr * 64 + mi * 16 + lrow][kk + quad * 8];
            #pragma unroll
            for (int ni = 0; ni < 4; ++ni)
                Bf[ni] = *(const bf16x8*)&Bbuf[wc * 64 + ni * 16 + lrow][kk + quad * 8];
            #pragma unroll
            for (int mi = 0; mi < 4; ++mi)
                #pragma unroll
                for (int ni = 0; ni < 4; ++ni)
                    acc[mi][ni] = __builtin_amdgcn_mfma_f32_16x16x32_bf16(
                        Af[mi], Bf[ni], acc[mi][ni], 0, 0, 0);
        }
        __syncthreads();
    }

    const int colb = ntile * 256 + wc * 64;
    float biasv[4];
    #pragma unroll
    for (int ni = 0; ni < 4; ++ni) biasv[ni] = bias[colb + ni * 16 + lrow];

    if (mode == 0) {
        #pragma unroll
        for (int mi = 0; mi < 4; ++mi) {
            int lr = wr * 64 + mi * 16 + quad * 4;
            #pragma unroll
            for (int reg = 0; reg < 4; ++reg) {
                int grow = row0 + lr + reg;
                if (grow >= M) continue;
                #pragma unroll
                for (int ni = 0; ni < 4; ++ni) {
                    int col = colb + ni * 16 + lrow;
                    outp[(size_t)grow * ldo + col] = acc[mi][ni][reg] + biasv[ni];
                }
            }
        }
    } else if (mode == 2) {
        bf16_t* outb = (bf16_t*)outp;
        #pragma unroll
        for (int mi = 0; mi < 4; ++mi) {
            int lr = wr * 64 + mi * 16 + quad * 4;
            #pragma unroll
            for (int reg = 0; reg < 4; ++reg) {
                int grow = row0 + lr + reg;
                if (grow >= M) continue;
                #pragma unroll
                for (int ni = 0; ni < 4; ++ni) {
                    int col = colb + ni * 16 + lrow;
                    outb[(size_t)grow * ldo + col] = (bf16_t)(acc[mi][ni][reg] + biasv[ni]);
                }
            }
        }
    } else {
        #pragma unroll
        for (int mi = 0; mi < 4; ++mi) {
            int lr = wr * 64 + mi * 16 + quad * 4;
            #pragma unroll
            for (int reg = 0; reg < 4; ++reg) {
                int grow = row0 + lr + reg;
                if (grow >= M) continue;
                #pragma unroll
                for (int ni = 0; ni < 4; ++ni) {
                    int col = colb + ni * 16 + lrow;
                    float v = acc[mi][ni][reg] + biasv[ni];
                    atomicMax(&poolbits[(size_t)sq_s[lr + reg] * 256 + col], enc_f(v));
                }
            }
        }
    }
}

// ---- sine PE helper ----
__device__ inline float pe_val(int j, float cz, float cy, float cx) {
    if (j >= 252) return 0.f;
    int dim = j / 84;
    int f = j % 84;
    int fi = (f >= 42) ? (f - 42) : f;
    float c  = (dim == 0) ? cz : ((dim == 1) ? cy : cx);
    float sp = (dim == 0) ? 480.f : ((dim == 1) ? 360.f : 32.f);
    float cn = c / sp * 6.28318530717958647692f;
    float tt = expf((float)fi * (9.210340371976184f / 42.f));
    float ang = cn / tt;
    return (f >= 42) ? cosf(ang) : sinf(ang);
}

// ---- per-segment max over sorted ef rows + fused PE + kmask ----
__global__ __launch_bounds__(256) void k_emb_reduce(
    const bf16_t* __restrict__ ef, const int* __restrict__ off,
    float* __restrict__ emb_feat, int* __restrict__ kmask)
{
    const int s = blockIdx.x, t = threadIdx.x;
    const int st = off[s], en = off[s + 1];
    float v0 = -3.0e38f, v1 = -3.0e38f;
    int j = st;
    for (; j + 1 < en; j += 2) {
        v0 = fmaxf(v0, (float)ef[(size_t)j * 256 + t]);
        v1 = fmaxf(v1, (float)ef[(size_t)(j + 1) * 256 + t]);
    }
    if (j < en) v0 = fmaxf(v0, (float)ef[(size_t)j * 256 + t]);
    float v = fmaxf(v0, v1);
    if (en == st) v = 0.f;

    int rem = s % Gk;
    float cz = (float)((rem / (Ye * Xe)) * 40);
    float cy = (float)(((rem / Xe) % Ye) * 15);
    float cx = (float)((rem % Xe) * 16);
    emb_feat[(size_t)s * 256 + t] = v + pe_val(t, cz, cy, cx);
    if (t == 0) kmask[s] = (en > st) ? 1 : 0;
}

__global__ __launch_bounds__(256) void k_pe_pool(
    const unsigned* __restrict__ bits, float* __restrict__ out)
{
    int s = blockIdx.x, j = threadIdx.x;
    unsigned m = bits[(size_t)s * D + j];
    float v = m ? dec_f(m) : 0.f;
    int rem = s % Gq;
    float cz = (float)((rem / (Yd * Xd)) * 8);
    float cy = (float)(((rem / Xd) % Yd) * 8);
    float cx = (float)((rem % Xd) * 8);
    out[(size_t)s * D + j] = v + pe_val(j, cz, cy, cx);
}

// ---- MFMA flash attention ----
__global__ __launch_bounds__(256) void k_attn_mfma(
    const bf16_t* __restrict__ Q, const bf16_t* __restrict__ KV,
    const int* __restrict__ kmask, float* __restrict__ O)
{
    __shared__ __align__(16) bf16_t Qs[64][40];
    __shared__ __align__(16) bf16_t Ks[192][40];
    __shared__ __align__(16) bf16_t Vts[32][200];
    __shared__ __align__(16) bf16_t Ps[4][16][200];
    __shared__ float mskf[192];

    const int bh = blockIdx.y;
    const int b = bh >> 3, h = bh & 7;
    const int t = threadIdx.x, wave = t >> 6, lane = t & 63;
    const int lrow = lane & 15, quad = lane >> 4;
    const int q0 = blockIdx.x * 64;

    {
        int r = t >> 2, part = t & 3;
        int qi = q0 + r;
        uint4 val = make_uint4(0u, 0u, 0u, 0u);
        if (qi < Gq)
            val = *(const uint4*)(Q + ((size_t)(b * Gq + qi)) * 256 + h * 32 + part * 8);
        *(uint4*)&Qs[r][part * 8] = val;
    }
    __syncthreads();

    const bf16x8 Aq = *(const bf16x8*)&Qs[wave * 16 + lrow][quad * 8];

    f32x4 oacc[2];
    oacc[0] = (f32x4){0.f, 0.f, 0.f, 0.f};
    oacc[1] = (f32x4){0.f, 0.f, 0.f, 0.f};
    float m_run[4], l_run[4];
    #pragma unroll
    for (int r = 0; r < 4; ++r) { m_run[r] = -3.0e38f; l_run[r] = 0.f; }

    for (int c0 = 0; c0 < Gk; c0 += 192) {
        __syncthreads();
        #pragma unroll
        for (int i = 0; i < 3; ++i) {
            int idx = i * 256 + t;
            int kk = idx >> 2, part = idx & 3;
            uint4 val = *(const uint4*)(KV + ((size_t)(b * Gk + c0 + kk)) * 512 + h * 32 + part * 8);
            *(uint4*)&Ks[kk][part * 8] = val;
        }
        #pragma unroll
        for (int i = 0; i < 3; ++i) {
            int idx = i * 256 + t;
            int kk = idx >> 2, part = idx & 3;
            bf16x8 v = *(const bf16x8*)(KV + ((size_t)(b * Gk + c0 + kk)) * 512 + 256 + h * 32 + part * 8);
            #pragma unroll
            for (int j = 0; j < 8; ++j)
                Vts[part * 8 + j][kk] = v[j];
        }
        if (t < 192) mskf[t] = kmask[b * Gk + c0 + t] ? 0.f : -1.0e9f;
        __syncthreads();

        float sreg[12][4];
        #pragma unroll
        for (int nt = 0; nt < 12; ++nt) {
            bf16x8 Bk = *(const bf16x8*)&Ks[nt * 16 + lrow][quad * 8];
            f32x4 sacc = __builtin_amdgcn_mfma_f32_16x16x32_bf16(
                Aq, Bk, (f32x4){0.f, 0.f, 0.f, 0.f}, 0, 0, 0);
            float pen = mskf[nt * 16 + lrow];
            #pragma unroll
            for (int r = 0; r < 4; ++r)
                sreg[nt][r] = sacc[r] * 0.17677669529663688f + pen;
        }

        float alpha[4];
        #pragma unroll
        for (int r = 0; r < 4; ++r) {
            float mx = sreg[0][r];
            #pragma unroll
            for (int nt = 1; nt < 12; ++nt) mx = fmaxf(mx, sreg[nt][r]);
            #pragma unroll
            for (int off = 1; off < 16; off <<= 1)
                mx = fmaxf(mx, __shfl_xor(mx, off));
            float mnew = fmaxf(m_run[r], mx);
            alpha[r] = __expf(m_run[r] - mnew);
            m_run[r] = mnew;
            l_run[r] *= alpha[r];
        }
        #pragma unroll
        for (int n2 = 0; n2 < 2; ++n2)
            #pragma unroll
            for (int r = 0; r < 4; ++r) oacc[n2][r] *= alpha[r];

        float psum[4] = {0.f, 0.f, 0.f, 0.f};
        #pragma unroll
        for (int nt = 0; nt < 12; ++nt) {
            #pragma unroll
            for (int r = 0; r < 4; ++r) {
                float p = __expf(sreg[nt][r] - m_run[r]);
                psum[r] += p;
                Ps[wave][quad * 4 + r][nt * 16 + lrow] = (bf16_t)p;
            }
        }
        #pragma unroll
        for (int r = 0; r < 4; ++r) {
            float s = psum[r];
            #pragma unroll
            for (int off = 1; off < 16; off <<= 1) s += __shfl_xor(s, off);
            l_run[r] += s;
        }

        #pragma unroll
        for (int ks = 0; ks < 6; ++ks) {
            bf16x8 Ap = *(const bf16x8*)&Ps[wave][lrow][ks * 32 + quad * 8];
            #pragma unroll
            for (int n2 = 0; n2 < 2; ++n2) {
                bf16x8 Bv = *(const bf16x8*)&Vts[n2 * 16 + lrow][ks * 32 + quad * 8];
                oacc[n2] = __builtin_amdgcn_mfma_f32_16x16x32_bf16(
                    Ap, Bv, oacc[n2], 0, 0, 0);
            }
        }
    }

    #pragma unroll
    for (int r = 0; r < 4; ++r) {
        int qi = q0 + wave * 16 + quad * 4 + r;
        if (qi >= Gq) continue;
        float inv = (l_run[r] > 0.f) ? (1.f / l_run[r]) : 0.f;
        #pragma unroll
        for (int n2 = 0; n2 < 2; ++n2)
            O[((size_t)(b * Gq + qi)) * 256 + h * 32 + n2 * 16 + lrow] = oacc[n2][r] * inv;
    }
}

// ---- residual + LayerNorm ----
__global__ __launch_bounds__(256) void k_ln(
    const float* __restrict__ oproj, const float* __restrict__ resid,
    const float* __restrict__ g, const float* __restrict__ bta,
    float* __restrict__ out)
{
    const int s = blockIdx.x, t = threadIdx.x;
    float h = resid[(size_t)s * D + t] + oproj[(size_t)s * D + t];

    float s1 = h, s2 = h * h;
    for (int o = 32; o > 0; o >>= 1) {
        s1 += __shfl_down(s1, o);
        s2 += __shfl_down(s2, o);
    }
    __shared__ float r1[4], r2[4];
    __shared__ float mu_s, rstd_s;
    int w = t >> 6;
    if ((t & 63) == 0) { r1[w] = s1; r2[w] = s2; }
    __syncthreads();
    if (t == 0) {
        float a = r1[0] + r1[1] + r1[2] + r1[3];
        float bsum = r2[0] + r2[1] + r2[2] + r2[3];
        float mu = a * (1.f / 256.f);
        float var = bsum * (1.f / 256.f) - mu * mu;
        mu_s = mu;
        rstd_s = rsqrtf(var + 1e-5f);
    }
    __syncthreads();
    out[(size_t)s * D + t] = (h - mu_s) * rstd_s * g[t] + bta[t];
}

// ---- final: vox = feat + mhca[seg_q], logits = vox @ W_seg + b_seg ----
#define PTS 16
__global__ __launch_bounds__(320) void k_logits(
    const float* __restrict__ feat, const float* __restrict__ mhca,
    const int* __restrict__ indices, const float* __restrict__ Wseg,
    const float* __restrict__ bseg, float* __restrict__ out)
{
    __shared__ float vox[PTS][D + 1];
    __shared__ float Wl[D * OUTC];
    __shared__ int sq[PTS];
    const int t = threadIdx.x;
    const int p0 = blockIdx.x * PTS;

    if (t < PTS) {
        const int* id = indices + (size_t)(p0 + t) * 4;
        sq[t] = ((id[0] * Zd + (id[1] >> 3)) * Yd + (id[2] >> 3)) * Xd + (id[3] >> 3);
    }
    for (int idx = t; idx < D * OUTC; idx += 320) Wl[idx] = Wseg[idx];
    __syncthreads();
    for (int idx = t; idx < PTS * D; idx += 320) {
        int r = idx / D, k = idx % D;
        vox[r][k] = feat[(size_t)(p0 + r) * D + k] + mhca[(size_t)sq[r] * D + k];
    }
    __syncthreads();

    const int r = t / OUTC, o = t % OUTC;
    float acc = bseg[o];
    #pragma unroll 4
    for (int k = 0; k < D; ++k) acc += vox[r][k] * Wl[k * OUTC + o];
    out[(size_t)(p0 + r) * OUTC + o] = acc;
}

extern "C" void kernel_launch(void* const* d_in, const int* in_sizes, int n_in,
                              void* d_out, int out_size, void* d_ws, size_t ws_size,
                              hipStream_t stream) {
    const float* features = (const float*)d_in[0];
    const float* W_pool = (const float*)d_in[1];
    const float* b_pool = (const float*)d_in[2];
    const float* W_emb  = (const float*)d_in[3];
    const float* b_emb  = (const float*)d_in[4];
    const float* Wq = (const float*)d_in[5];
    const float* bq = (const float*)d_in[6];
    const float* Wk = (const float*)d_in[7];
    const float* bk = (const float*)d_in[8];
    const float* Wv = (const float*)d_in[9];
    const float* bv = (const float*)d_in[10];
    const float* Wo = (const float*)d_in[11];
    const float* bo = (const float*)d_in[12];
    const float* ln_g = (const float*)d_in[13];
    const float* ln_b = (const float*)d_in[14];
    const float* W_seg = (const float*)d_in[15];
    const float* b_seg = (const float*)d_in[16];
    const int* indices = (const int*)d_in[17];
    float* out = (float*)d_out;

    float* ws = (float*)d_ws;
    const size_t SQD = (size_t)Sq * D;   // 5,529,600 floats
    // Phase-overlapped arena, ALL offsets in float units (bf16 sizes halved):
    //   ef_sorted bf16 120000x256 = 15,360,000 fl   [0 .. 15,360,000)   phase 1
    //   poolbits  [0 .. 5,529,600)                                      phase 2 (ef dead)
    //   attnO     [0 .. 5,529,600)                                      phase 3
    //   mhca      [0 .. 5,529,600)                                      phase 4
    //   pool_feat [5,529,600 .. 11,059,200)                             phase 2-4
    //   Qb bf16 21600x256 = 2,764,800 fl [11,059,200 .. 13,824,000)     phase 3
    //   KVb bf16 1152x512 = 294,912 fl   [13,824,000 .. 14,118,912)     phase 3
    //   oproj     [11,059,200 .. 16,588,800)                            phase 4 (Qb/KVb dead)
    bf16_t* ef_sorted = (bf16_t*)(ws);
    unsigned* poolbits = (unsigned*)(ws);
    float* attnO = ws;
    float* mhca  = ws;
    float* pool_feat = ws + SQD;
    bf16_t* Qb  = (bf16_t*)(ws + 2 * SQD);           // 11,059,200
    bf16_t* KVb = (bf16_t*)(ws + 13824000);
    float* oproj = ws + 2 * SQD;

    // Persistent tail at PB = 16,588,800 floats:
    const size_t PB = 16588800;
    float* emb_feat = ws + PB;                       // 294,912 fl
    int* kmask = (int*)(ws + PB + 294912);           // 1,152
    int* cnt   = (int*)(ws + PB + 296064);           // 1,152
    int* off   = (int*)(ws + PB + 297216);           // 1,153
    int* wrk   = (int*)(ws + PB + 298372);           // 1,152
    int* perm  = (int*)(ws + PB + 299524);           // 120,000
    bf16_t* Wpt = (bf16_t*)(ws + PB + 419524);       // 32,768 fl
    bf16_t* Wet = (bf16_t*)(ws + PB + 452292);       // 32,768 fl
    bf16_t* Wqt = (bf16_t*)(ws + PB + 485060);       // 32,768 fl
    bf16_t* Wkv = (bf16_t*)(ws + PB + 517828);       // 65,536 fl
    bf16_t* Wot = (bf16_t*)(ws + PB + 583364);       // 32,768 fl
    float* bkv = ws + PB + 616132;                   // 512 fl; end 616,644

    k_prep<<<1537, 256, 0, stream>>>(W_pool, W_emb, Wq, Wk, Wv, Wo, bk, bv,
                                     Wpt, Wet, Wqt, Wkv, Wot, bkv);

    // ---- counting sort by seg_k ----
    hipMemsetAsync(cnt, 0, Sk * sizeof(int), stream);
    k_hist<<<(N_PTS + 255) / 256, 256, 0, stream>>>(indices, cnt);
    k_scan<<<1, 256, 0, stream>>>(cnt, off, wrk);
    k_fill<<<(N_PTS + 255) / 256, 256, 0, stream>>>(indices, wrk, perm);

    // ---- emb branch: GEMM (sorted rows, bf16 out) -> segment reduce + PE ----
    {
        dim3 g(1, (N_PTS + 127) / 128);
        k_gemm<<<g, 512, 0, stream>>>(features, N_PTS, Wet, b_emb, 2,
                                      (float*)ef_sorted, 256, nullptr, perm, nullptr);
    }
    k_emb_reduce<<<Sk, 256, 0, stream>>>(ef_sorted, off, emb_feat, kmask);

    // ---- pool branch: atomic scatter-max GEMM -> PE ----
    hipMemsetAsync(poolbits, 0, SQD * sizeof(unsigned), stream);
    {
        dim3 g(1, (N_PTS + 127) / 128);
        k_gemm<<<g, 512, 0, stream>>>(features, N_PTS, Wpt, b_pool, 1,
                                      nullptr, 0, indices, nullptr, poolbits);
    }
    k_pe_pool<<<Sq, 256, 0, stream>>>(poolbits, pool_feat);

    // ---- projections ----
    {
        dim3 g(1, (Sq + 127) / 128);
        k_gemm<<<g, 512, 0, stream>>>(pool_feat, Sq, Wqt, bq, 2,
                                      (float*)Qb, 256, nullptr, nullptr, nullptr);
    }
    {
        dim3 g(2, (Sk + 127) / 128);
        k_gemm<<<g, 512, 0, stream>>>(emb_feat, Sk, Wkv, bkv, 2,
                                      (float*)KVb, 512, nullptr, nullptr, nullptr);
    }

    {
        dim3 ag((Gq + 63) / 64, BATCH * NH);
        k_attn_mfma<<<ag, 256, 0, stream>>>(Qb, KVb, kmask, attnO);
    }

    {
        dim3 g(1, (Sq + 127) / 128);
        k_gemm<<<g, 512, 0, stream>>>(attnO, Sq, Wot, bo, 0,
                                      oproj, 256, nullptr, nullptr, nullptr);
    }

    k_ln<<<Sq, 256, 0, stream>>>(oproj, pool_feat, ln_g, ln_b, mhca);

    k_logits<<<N_PTS / PTS, 320, 0, stream>>>(
        features, mhca, indices, W_seg, b_seg, out);
}